// Round 1
// baseline (356.220 us; speedup 1.0000x reference)
//
#include <hip/hip_runtime.h>
#include <float.h>

#define MARGIN 0.1f

// Kernel 1: one block per output row i.
//   row      = sim_mat[idx[i], :]
//   pos      = min over j of row[j] where targets[j]==targets[i] && j != idx[i]
//   neg      = max over j of row[j] where targets[j]!=targets[i]
//   loss[i]  = max(neg - pos + MARGIN, 0)
__global__ __launch_bounds__(256) void triplet_row_kernel(
    const float* __restrict__ sim,
    const int* __restrict__ targets,
    const int* __restrict__ idx,
    float* __restrict__ row_loss,
    int n)
{
    const int i = blockIdx.x;
    const int r = idx[i];          // row index to gather
    const int self_col = r;        // self_mask: idx[i] == column j
    const int ti = targets[i];

    const float* __restrict__ row = sim + (long long)r * (long long)n;

    float pmin = FLT_MAX;
    float nmax = -FLT_MAX;

    const int tid = threadIdx.x;
    const int nvec = n >> 2;                   // float4 count per row
    const float4* __restrict__ row4 = (const float4*)row;
    const int4* __restrict__ tgt4 = (const int4*)targets;

    for (int v = tid; v < nvec; v += 256) {
        float4 s = row4[v];
        int4 tg = tgt4[v];
        const int j0 = v << 2;

        // element 0
        {
            bool same = (tg.x == ti);
            float pv = (same && (j0 + 0) != self_col) ? s.x : FLT_MAX;
            float nv = same ? -FLT_MAX : s.x;
            pmin = fminf(pmin, pv);
            nmax = fmaxf(nmax, nv);
        }
        // element 1
        {
            bool same = (tg.y == ti);
            float pv = (same && (j0 + 1) != self_col) ? s.y : FLT_MAX;
            float nv = same ? -FLT_MAX : s.y;
            pmin = fminf(pmin, pv);
            nmax = fmaxf(nmax, nv);
        }
        // element 2
        {
            bool same = (tg.z == ti);
            float pv = (same && (j0 + 2) != self_col) ? s.z : FLT_MAX;
            float nv = same ? -FLT_MAX : s.z;
            pmin = fminf(pmin, pv);
            nmax = fmaxf(nmax, nv);
        }
        // element 3
        {
            bool same = (tg.w == ti);
            float pv = (same && (j0 + 3) != self_col) ? s.w : FLT_MAX;
            float nv = same ? -FLT_MAX : s.w;
            pmin = fminf(pmin, pv);
            nmax = fmaxf(nmax, nv);
        }
    }

    // scalar tail (n not divisible by 4) — no-op for n=8192
    for (int j = (nvec << 2) + tid; j < n; j += 256) {
        float s = row[j];
        bool same = (targets[j] == ti);
        float pv = (same && j != self_col) ? s : FLT_MAX;
        float nv = same ? -FLT_MAX : s;
        pmin = fminf(pmin, pv);
        nmax = fmaxf(nmax, nv);
    }

    // wave-64 reduction
    #pragma unroll
    for (int off = 32; off > 0; off >>= 1) {
        pmin = fminf(pmin, __shfl_down(pmin, off));
        nmax = fmaxf(nmax, __shfl_down(nmax, off));
    }

    // cross-wave reduction (256 threads = 4 waves)
    __shared__ float s_pmin[4];
    __shared__ float s_nmax[4];
    const int wave = tid >> 6;
    const int lane = tid & 63;
    if (lane == 0) {
        s_pmin[wave] = pmin;
        s_nmax[wave] = nmax;
    }
    __syncthreads();
    if (tid == 0) {
        float p = s_pmin[0];
        float q = s_nmax[0];
        #pragma unroll
        for (int w = 1; w < 4; ++w) {
            p = fminf(p, s_pmin[w]);
            q = fmaxf(q, s_nmax[w]);
        }
        float loss = fmaxf(q - p + MARGIN, 0.0f);
        row_loss[i] = loss;
    }
}

// Kernel 2: reduce n row losses to the mean. Single block, deterministic.
__global__ __launch_bounds__(1024) void mean_reduce_kernel(
    const float* __restrict__ row_loss,
    float* __restrict__ out,
    int n)
{
    const int tid = threadIdx.x;
    float acc = 0.0f;
    for (int i = tid; i < n; i += 1024) acc += row_loss[i];

    #pragma unroll
    for (int off = 32; off > 0; off >>= 1)
        acc += __shfl_down(acc, off);

    __shared__ float s_sum[16];    // 1024 threads = 16 waves
    const int wave = tid >> 6;
    const int lane = tid & 63;
    if (lane == 0) s_sum[wave] = acc;
    __syncthreads();
    if (tid == 0) {
        float total = 0.0f;
        #pragma unroll
        for (int w = 0; w < 16; ++w) total += s_sum[w];
        out[0] = total / (float)n;
    }
}

extern "C" void kernel_launch(void* const* d_in, const int* in_sizes, int n_in,
                              void* d_out, int out_size, void* d_ws, size_t ws_size,
                              hipStream_t stream) {
    const float* sim = (const float*)d_in[0];
    const int* targets = (const int*)d_in[1];
    const int* idx = (const int*)d_in[2];
    const int n = in_sizes[2];     // number of output rows (= idx length = 8192)

    float* row_loss = (float*)d_ws;
    float* out = (float*)d_out;

    triplet_row_kernel<<<n, 256, 0, stream>>>(sim, targets, idx, row_loss, n);
    mean_reduce_kernel<<<1, 1024, 0, stream>>>(row_loss, out, n);
}

// Round 3
// 336.458 us; speedup vs baseline: 1.0587x; 1.0587x over previous
//
#include <hip/hip_runtime.h>
#include <float.h>

#define MARGIN 0.1f

// Native clang vector types (required by __builtin_nontemporal_load;
// HIP_vector_type structs are rejected).
typedef float  fx4 __attribute__((ext_vector_type(4)));
typedef int    ix4 __attribute__((ext_vector_type(4)));

// Process one (value, target) element into running hardest-pos / hardest-neg.
__device__ __forceinline__ void acc_elem(float s, int tg, int ti, int j, int self_col,
                                         float& pmin, float& nmax) {
    const bool same = (tg == ti);
    const float pv = (same && j != self_col) ? s : FLT_MAX;
    const float nv = same ? -FLT_MAX : s;
    pmin = fminf(pmin, pv);
    nmax = fmaxf(nmax, nv);
}

__device__ __forceinline__ void acc_vec4(fx4 s, ix4 tg, int ti, int j0, int self_col,
                                         float& pmin, float& nmax) {
    acc_elem(s.x, tg.x, ti, j0 + 0, self_col, pmin, nmax);
    acc_elem(s.y, tg.y, ti, j0 + 1, self_col, pmin, nmax);
    acc_elem(s.z, tg.z, ti, j0 + 2, self_col, pmin, nmax);
    acc_elem(s.w, tg.w, ti, j0 + 3, self_col, pmin, nmax);
}

// Kernel 1: one 256-thread block per output row i.
//   row     = sim_mat[idx[i], :]
//   pos     = min over j: targets[j]==targets[i] && j != idx[i]
//   neg     = max over j: targets[j]!=targets[i]
//   loss[i] = max(neg - pos + MARGIN, 0)
__global__ __launch_bounds__(256) void triplet_row_kernel(
    const float* __restrict__ sim,
    const int* __restrict__ targets,
    const int* __restrict__ idx,
    float* __restrict__ row_loss,
    int n)
{
    const int i = blockIdx.x;
    const int r = idx[i];          // row to gather
    const int self_col = r;        // self exclusion column
    const int ti = targets[i];

    const fx4* __restrict__ row4 = (const fx4*)(sim + (long long)r * (long long)n);
    const ix4* __restrict__ tgt4 = (const ix4*)targets;

    float pmin = FLT_MAX;
    float nmax = -FLT_MAX;

    const int tid = threadIdx.x;
    const int nvec = n >> 2;       // float4 count per row (2048 for n=8192)

    // Batch-4 main loop: issue 8 loads (4 sim + 4 targets) back-to-back
    // before consuming — ~8 VMEM ops in flight per thread for latency hiding.
    int v = tid;
    for (; v + 768 < nvec; v += 1024) {
        const fx4 s0 = __builtin_nontemporal_load(&row4[v]);
        const fx4 s1 = __builtin_nontemporal_load(&row4[v + 256]);
        const fx4 s2 = __builtin_nontemporal_load(&row4[v + 512]);
        const fx4 s3 = __builtin_nontemporal_load(&row4[v + 768]);
        const ix4 t0 = tgt4[v];
        const ix4 t1 = tgt4[v + 256];
        const ix4 t2 = tgt4[v + 512];
        const ix4 t3 = tgt4[v + 768];
        acc_vec4(s0, t0, ti, (v) << 2, self_col, pmin, nmax);
        acc_vec4(s1, t1, ti, (v + 256) << 2, self_col, pmin, nmax);
        acc_vec4(s2, t2, ti, (v + 512) << 2, self_col, pmin, nmax);
        acc_vec4(s3, t3, ti, (v + 768) << 2, self_col, pmin, nmax);
    }
    // vec tail
    for (; v < nvec; v += 256) {
        const fx4 s = __builtin_nontemporal_load(&row4[v]);
        const ix4 tg = tgt4[v];
        acc_vec4(s, tg, ti, v << 2, self_col, pmin, nmax);
    }
    // scalar tail (n not divisible by 4) — no-op for n=8192
    const float* __restrict__ row = (const float*)row4;
    for (int j = (nvec << 2) + tid; j < n; j += 256) {
        acc_elem(row[j], targets[j], ti, j, self_col, pmin, nmax);
    }

    // wave-64 butterfly reduction
    #pragma unroll
    for (int off = 32; off > 0; off >>= 1) {
        pmin = fminf(pmin, __shfl_down(pmin, off));
        nmax = fmaxf(nmax, __shfl_down(nmax, off));
    }

    // cross-wave reduction (4 waves)
    __shared__ float s_pmin[4];
    __shared__ float s_nmax[4];
    const int wave = tid >> 6;
    const int lane = tid & 63;
    if (lane == 0) {
        s_pmin[wave] = pmin;
        s_nmax[wave] = nmax;
    }
    __syncthreads();
    if (tid == 0) {
        float p = fminf(fminf(s_pmin[0], s_pmin[1]), fminf(s_pmin[2], s_pmin[3]));
        float q = fmaxf(fmaxf(s_nmax[0], s_nmax[1]), fmaxf(s_nmax[2], s_nmax[3]));
        row_loss[i] = fmaxf(q - p + MARGIN, 0.0f);
    }
}

// Kernel 2: reduce n row losses to the mean. Single block, deterministic.
__global__ __launch_bounds__(1024) void mean_reduce_kernel(
    const float* __restrict__ row_loss,
    float* __restrict__ out,
    int n)
{
    const int tid = threadIdx.x;
    float acc = 0.0f;
    for (int i = tid; i < n; i += 1024) acc += row_loss[i];

    #pragma unroll
    for (int off = 32; off > 0; off >>= 1)
        acc += __shfl_down(acc, off);

    __shared__ float s_sum[16];    // 16 waves
    const int wave = tid >> 6;
    const int lane = tid & 63;
    if (lane == 0) s_sum[wave] = acc;
    __syncthreads();
    if (tid == 0) {
        float total = 0.0f;
        #pragma unroll
        for (int w = 0; w < 16; ++w) total += s_sum[w];
        out[0] = total / (float)n;
    }
}

extern "C" void kernel_launch(void* const* d_in, const int* in_sizes, int n_in,
                              void* d_out, int out_size, void* d_ws, size_t ws_size,
                              hipStream_t stream) {
    const float* sim = (const float*)d_in[0];
    const int* targets = (const int*)d_in[1];
    const int* idx = (const int*)d_in[2];
    const int n = in_sizes[2];     // rows (= idx length = 8192)

    float* row_loss = (float*)d_ws;
    float* out = (float*)d_out;

    triplet_row_kernel<<<n, 256, 0, stream>>>(sim, targets, idx, row_loss, n);
    mean_reduce_kernel<<<1, 1024, 0, stream>>>(row_loss, out, n);
}

// Round 4
// 335.776 us; speedup vs baseline: 1.0609x; 1.0020x over previous
//
#include <hip/hip_runtime.h>
#include <float.h>
#include <limits.h>

#define MARGIN 0.1f
#define BLK 512          // threads per block (8 waves)
#define ROWS 4           // rows processed per block
#define KCHUNK 4         // float4 chunks per thread per row (BLK*KCHUNK*4 == n)

// Native clang vector types (__builtin_nontemporal_load rejects HIP_vector_type).
typedef float fx4 __attribute__((ext_vector_type(4)));
typedef int   ix4 __attribute__((ext_vector_type(4)));

__device__ __forceinline__ void acc_elem(float s, int tg, int ti, int j, int self_col,
                                         float& pmin, float& nmax) {
    const bool same = (tg == ti);
    const float pv = (same && j != self_col) ? s : FLT_MAX;
    const float nv = same ? -FLT_MAX : s;
    pmin = fminf(pmin, pv);
    nmax = fmaxf(nmax, nv);
}

__device__ __forceinline__ void acc_vec4(fx4 s, ix4 tg, int ti, int j0, int self_col,
                                         float& pmin, float& nmax) {
    acc_elem(s.x, tg.x, ti, j0 + 0, self_col, pmin, nmax);
    acc_elem(s.y, tg.y, ti, j0 + 1, self_col, pmin, nmax);
    acc_elem(s.z, tg.z, ti, j0 + 2, self_col, pmin, nmax);
    acc_elem(s.w, tg.w, ti, j0 + 3, self_col, pmin, nmax);
}

// One block handles ROWS consecutive output rows. Targets are loaded once per
// thread into registers and reused across all ROWS rows.
__global__ __launch_bounds__(BLK) void triplet_rows_kernel(
    const float* __restrict__ sim,
    const int* __restrict__ targets,
    const int* __restrict__ idx,
    float* __restrict__ row_loss,
    int n)
{
    const int tid = threadIdx.x;
    const int nvec = n >> 2;                 // float4 count per row
    const int i0 = blockIdx.x * ROWS;
    const ix4* __restrict__ tgt4 = (const ix4*)targets;

    // Cache this thread's target columns in registers (reused for all rows).
    ix4 tg[KCHUNK];
    int vbase[KCHUNK];
    #pragma unroll
    for (int k = 0; k < KCHUNK; ++k) {
        const int v = tid + k * BLK;
        vbase[k] = v;
        if (v < nvec) tg[k] = tgt4[v];
    }

    __shared__ float s_p[ROWS][BLK / 64];
    __shared__ float s_n[ROWS][BLK / 64];

    #pragma unroll
    for (int rr = 0; rr < ROWS; ++rr) {
        const int i = i0 + rr;
        if (i >= n) break;                   // uniform across block
        const int r = idx[i];
        const int ti = targets[i];
        const int self_col = r;
        const fx4* __restrict__ row4 = (const fx4*)(sim + (size_t)r * (size_t)n);

        // Issue all sim loads for this row back-to-back (in-flight depth 4).
        fx4 s[KCHUNK];
        #pragma unroll
        for (int k = 0; k < KCHUNK; ++k)
            if (vbase[k] < nvec) s[k] = __builtin_nontemporal_load(&row4[vbase[k]]);

        float pmin = FLT_MAX, nmax = -FLT_MAX;
        #pragma unroll
        for (int k = 0; k < KCHUNK; ++k)
            if (vbase[k] < nvec)
                acc_vec4(s[k], tg[k], ti, vbase[k] << 2, self_col, pmin, nmax);

        // scalar tail (n % 4 != 0) — no-op for n=8192
        for (int j = (nvec << 2) + tid; j < n; j += BLK)
            acc_elem(sim[(size_t)r * (size_t)n + j], targets[j], ti, j, self_col,
                     pmin, nmax);

        // wave-64 butterfly reduction
        #pragma unroll
        for (int off = 32; off > 0; off >>= 1) {
            pmin = fminf(pmin, __shfl_down(pmin, off));
            nmax = fmaxf(nmax, __shfl_down(nmax, off));
        }
        const int wave = tid >> 6;
        const int lane = tid & 63;
        if (lane == 0) { s_p[rr][wave] = pmin; s_n[rr][wave] = nmax; }
    }

    __syncthreads();                          // single barrier for all rows

    // First ROWS threads finalize one row each.
    if (tid < ROWS) {
        const int i = i0 + tid;
        if (i < n) {
            float p = s_p[tid][0];
            float q = s_n[tid][0];
            #pragma unroll
            for (int w = 1; w < BLK / 64; ++w) {
                p = fminf(p, s_p[tid][w]);
                q = fmaxf(q, s_n[tid][w]);
            }
            row_loss[i] = fmaxf(q - p + MARGIN, 0.0f);
        }
    }
}

// Kernel 2: reduce n row losses to the mean. Single block, deterministic.
__global__ __launch_bounds__(1024) void mean_reduce_kernel(
    const float* __restrict__ row_loss,
    float* __restrict__ out,
    int n)
{
    const int tid = threadIdx.x;
    float acc = 0.0f;
    for (int i = tid; i < n; i += 1024) acc += row_loss[i];

    #pragma unroll
    for (int off = 32; off > 0; off >>= 1)
        acc += __shfl_down(acc, off);

    __shared__ float s_sum[16];
    const int wave = tid >> 6;
    const int lane = tid & 63;
    if (lane == 0) s_sum[wave] = acc;
    __syncthreads();
    if (tid == 0) {
        float total = 0.0f;
        #pragma unroll
        for (int w = 0; w < 16; ++w) total += s_sum[w];
        out[0] = total / (float)n;
    }
}

extern "C" void kernel_launch(void* const* d_in, const int* in_sizes, int n_in,
                              void* d_out, int out_size, void* d_ws, size_t ws_size,
                              hipStream_t stream) {
    const float* sim = (const float*)d_in[0];
    const int* targets = (const int*)d_in[1];
    const int* idx = (const int*)d_in[2];
    const int n = in_sizes[2];      // rows (= idx length = 8192)

    float* row_loss = (float*)d_ws;
    float* out = (float*)d_out;

    const int grid = (n + ROWS - 1) / ROWS;
    triplet_rows_kernel<<<grid, BLK, 0, stream>>>(sim, targets, idx, row_loss, n);
    mean_reduce_kernel<<<1, 1024, 0, stream>>>(row_loss, out, n);
}